// Round 3
// baseline (300.961 us; speedup 1.0000x reference)
//
#include <hip/hip_runtime.h>
#include <hip/hip_bf16.h>

typedef unsigned short u16;
typedef __bf16 bf16x8 __attribute__((ext_vector_type(8)));
typedef float f32x4 __attribute__((ext_vector_type(4)));

__device__ __forceinline__ f32x4 mfma16(bf16x8 a, bf16x8 b, f32x4 c) {
    return __builtin_amdgcn_mfma_f32_16x16x32_bf16(a, b, c, 0, 0, 0);
}

// fp32 -> bf16 bits, round-to-nearest-even
__device__ __forceinline__ u16 f2b(float x) {
    union { float f; unsigned u; } a; a.f = x;
    unsigned r = a.u + 0x7fffu + ((a.u >> 16) & 1u);
    return (u16)(r >> 16);
}

// ---------------- QKV GEMM (fused fp32->bf16 cast in staging) ----------------
// [8192,512]fp32 x [1536,512]fp32^T -> q,k [B*H,S,64] bf16, v [B*H,64,S] bf16
// q pre-scaled by 0.125/ln(2) so attention uses exp2 directly.
__global__ __launch_bounds__(256) void k_gemm_qkv(const float* __restrict__ x,
                                                  const float* __restrict__ wqkv,
                                                  const float* __restrict__ bias,
                                                  u16* __restrict__ qkvout) {
    __shared__ u16 As[128][40];
    __shared__ u16 Ws[64][40];
    const int tid = threadIdx.x;
    const int w = tid >> 6, lane = tid & 63, l15 = lane & 15, quad = lane >> 4;
    const int mb = blockIdx.x * 128, nb = blockIdx.y * 64;

    f32x4 acc[2][4];
#pragma unroll
    for (int i = 0; i < 2; i++)
#pragma unroll
        for (int j = 0; j < 4; j++) acc[i][j] = (f32x4){0.f, 0.f, 0.f, 0.f};

    for (int k0 = 0; k0 < 512; k0 += 32) {
        {   // stage A: 128x32 fp32 -> bf16 ; 16 vals/thread
            int row = tid >> 1, seg = (tid & 1) * 16;
            const float* g = &x[(size_t)(mb + row) * 512 + k0 + seg];
            u16 o[16];
#pragma unroll
            for (int e = 0; e < 4; e++) {
                float4 f = *(const float4*)(g + e * 4);
                o[e * 4 + 0] = f2b(f.x); o[e * 4 + 1] = f2b(f.y);
                o[e * 4 + 2] = f2b(f.z); o[e * 4 + 3] = f2b(f.w);
            }
            *(uint4*)&As[row][seg]     = *(uint4*)&o[0];
            *(uint4*)&As[row][seg + 8] = *(uint4*)&o[8];
            // stage W: 64x32 fp32 -> bf16 ; 8 vals/thread
            int wrow = tid >> 2, wseg = (tid & 3) * 8;
            const float* gw = &wqkv[(size_t)(nb + wrow) * 512 + k0 + wseg];
            float4 h0 = *(const float4*)gw, h1 = *(const float4*)(gw + 4);
            u16 ow[8] = { f2b(h0.x), f2b(h0.y), f2b(h0.z), f2b(h0.w),
                          f2b(h1.x), f2b(h1.y), f2b(h1.z), f2b(h1.w) };
            *(uint4*)&Ws[wrow][wseg] = *(uint4*)ow;
        }
        __syncthreads();
        bf16x8 a0 = *(const bf16x8*)&As[w * 32 + l15][quad * 8];
        bf16x8 a1 = *(const bf16x8*)&As[w * 32 + 16 + l15][quad * 8];
#pragma unroll
        for (int nt = 0; nt < 4; nt++) {
            bf16x8 bfr = *(const bf16x8*)&Ws[nt * 16 + l15][quad * 8];
            acc[0][nt] = mfma16(a0, bfr, acc[0][nt]);
            acc[1][nt] = mfma16(a1, bfr, acc[1][nt]);
        }
        __syncthreads();
    }
    // epilogue: q,k -> [B*H][S][64]; v -> transposed [B*H][64][S]
    const int seg = nb >> 9;          // 0=q 1=k 2=v
    const int hh  = (nb >> 6) & 7;
    u16* obase = qkvout + (size_t)seg * (16ull * 4096 * 64);
    if (seg < 2) {
        const float sc = (seg == 0) ? 0.125f * 1.44269504088896340736f : 1.0f;
#pragma unroll
        for (int mt = 0; mt < 2; mt++)
#pragma unroll
            for (int nt = 0; nt < 4; nt++)
#pragma unroll
                for (int r = 0; r < 4; r++) {
                    int m = mb + w * 32 + mt * 16 + quad * 4 + r;
                    int dloc = nt * 16 + l15;
                    float vv = (acc[mt][nt][r] + bias[nb + dloc]) * sc;
                    int b = m >> 12, s = m & 4095;
                    obase[((size_t)((b * 8 + hh) * 4096 + s)) * 64 + dloc] = f2b(vv);
                }
    } else {
#pragma unroll
        for (int mt = 0; mt < 2; mt++)
#pragma unroll
            for (int nt = 0; nt < 4; nt++) {
                int m0 = mb + w * 32 + mt * 16 + quad * 4;
                int b = m0 >> 12, s0 = m0 & 4095;
                int dloc = nt * 16 + l15;
                u16 o[4];
#pragma unroll
                for (int r = 0; r < 4; r++)
                    o[r] = f2b(acc[mt][nt][r] + bias[nb + dloc]);
                *(uint2*)&obase[((size_t)((b * 8 + hh) * 64 + dloc)) * 4096 + s0] = *(uint2*)o;
            }
    }
}

// ---------------- flash attention v3 (inverted-window mask) -----------------
// block = 128 threads = 2 waves; each wave owns 64 q-rows (4 groups of 16).
// K/V frags reused 4x per LDS read; fixed-max softmax (exp2), deferred row-sum.
__global__ __launch_bounds__(128) void k_attn(const u16* __restrict__ qkv,
                                              u16* __restrict__ ctx,
                                              const int* __restrict__ win) {
    __shared__ u16 Ks[64][72];    // [key][d]
    __shared__ u16 Vt[64][72];    // [d][key]
    __shared__ u16 Ps[128][72];   // [qrow local][key], per-wave 64-row slabs
    const int tid = threadIdx.x;
    const int w = tid >> 6, lane = tid & 63, l15 = lane & 15, quad = lane >> 4;
    const int bh = blockIdx.y;
    const int qb0 = blockIdx.x * 128;
    const int W = win[0];
    const u16* qg = qkv;
    const u16* kg = qkv + 16ull * 4096 * 64;
    const u16* vg = qkv + 32ull * 4096 * 64;   // [bh][64][4096]
    const size_t bhb = (size_t)bh * 4096 * 64;

    // Q fragments: B-operand of S^T = K*Q^T  (lane l15 = qrow within group)
    bf16x8 qf[4][2];
#pragma unroll
    for (int g = 0; g < 4; g++) {
        const u16* qrow = &qg[bhb + (size_t)(qb0 + w * 64 + g * 16 + l15) * 64];
        qf[g][0] = *(const bf16x8*)&qrow[quad * 8];
        qf[g][1] = *(const bf16x8*)&qrow[32 + quad * 8];
    }

    f32x4 O[4][4];
#pragma unroll
    for (int g = 0; g < 4; g++)
#pragma unroll
        for (int nt = 0; nt < 4; nt++) O[g][nt] = (f32x4){0.f, 0.f, 0.f, 0.f};
    float lsum[4] = {0.f, 0.f, 0.f, 0.f};

    const int srow = tid >> 1, shalf = (tid & 1) * 32;
    const u16* kgr = &kg[bhb + (size_t)srow * 64 + shalf];
    const u16* vgr = &vg[((size_t)bh * 64 + srow) * 4096 + shalf];

    for (int kb = 0; kb < 4096; kb += 64) {
        if (max(qb0 + 127 - kb, kb + 63 - qb0) <= W) continue;  // fully masked tile
        bool partial = (kb + 63 >= qb0 - W) && (kb <= qb0 + 127 + W);
        {   // stage K (row-major) and Vt (d-major in global): all b128
            const u16* kp = kgr + (size_t)kb * 64;
            *(uint4*)&Ks[srow][shalf]      = *(const uint4*)kp;
            *(uint4*)&Ks[srow][shalf + 8]  = *(const uint4*)(kp + 8);
            *(uint4*)&Ks[srow][shalf + 16] = *(const uint4*)(kp + 16);
            *(uint4*)&Ks[srow][shalf + 24] = *(const uint4*)(kp + 24);
            const u16* vp = vgr + kb;
            *(uint4*)&Vt[srow][shalf]      = *(const uint4*)vp;
            *(uint4*)&Vt[srow][shalf + 8]  = *(const uint4*)(vp + 8);
            *(uint4*)&Vt[srow][shalf + 16] = *(const uint4*)(vp + 16);
            *(uint4*)&Vt[srow][shalf + 24] = *(const uint4*)(vp + 24);
        }
        __syncthreads();
        // K fragments once, reused across 4 q-row groups
        bf16x8 kf[4][2];
#pragma unroll
        for (int nt = 0; nt < 4; nt++) {
            kf[nt][0] = *(const bf16x8*)&Ks[nt * 16 + l15][quad * 8];
            kf[nt][1] = *(const bf16x8*)&Ks[nt * 16 + l15][32 + quad * 8];
        }
#pragma unroll
        for (int g = 0; g < 4; g++) {
            f32x4 C[4];
#pragma unroll
            for (int nt = 0; nt < 4; nt++) {
                f32x4 z = (f32x4){0.f, 0.f, 0.f, 0.f};
                C[nt] = mfma16(kf[nt][0], qf[g][0], z);
                C[nt] = mfma16(kf[nt][1], qf[g][1], C[nt]);
            }
            // p = 2^s; masked -> 0; per-lane partial sums; pack -> Ps
            if (!partial) {
#pragma unroll
                for (int nt = 0; nt < 4; nt++) {
                    u16 o[4];
#pragma unroll
                    for (int r = 0; r < 4; r++) {
                        float p = __builtin_amdgcn_exp2f(C[nt][r]);
                        lsum[g] += p;
                        o[r] = f2b(p);
                    }
                    *(uint2*)&Ps[w * 64 + g * 16 + l15][nt * 16 + quad * 4] = *(uint2*)o;
                }
            } else {
                int qr = qb0 + w * 64 + g * 16 + l15;
#pragma unroll
                for (int nt = 0; nt < 4; nt++) {
                    u16 o[4];
#pragma unroll
                    for (int r = 0; r < 4; r++) {
                        int key = kb + nt * 16 + quad * 4 + r;
                        int dd = qr - key; dd = dd < 0 ? -dd : dd;
                        float p = (dd <= W) ? 0.f : __builtin_amdgcn_exp2f(C[nt][r]);
                        lsum[g] += p;
                        o[r] = f2b(p);
                    }
                    *(uint2*)&Ps[w * 64 + g * 16 + l15][nt * 16 + quad * 4] = *(uint2*)o;
                }
            }
        }
        // O += P V  (V-frags reused across 4 groups; Ps wave-local, no barrier)
#pragma unroll
        for (int ks = 0; ks < 2; ks++) {
            bf16x8 pa[4];
#pragma unroll
            for (int g = 0; g < 4; g++)
                pa[g] = *(const bf16x8*)&Ps[w * 64 + g * 16 + l15][ks * 32 + quad * 8];
#pragma unroll
            for (int nt = 0; nt < 4; nt++) {
                bf16x8 vb = *(const bf16x8*)&Vt[nt * 16 + l15][ks * 32 + quad * 8];
#pragma unroll
                for (int g = 0; g < 4; g++)
                    O[g][nt] = mfma16(pa[g], vb, O[g][nt]);
            }
        }
        __syncthreads();
    }
    // finish deferred row-sums: reduce across the 4 quads (same l15)
#pragma unroll
    for (int g = 0; g < 4; g++) {
        lsum[g] += __shfl_xor(lsum[g], 16);
        lsum[g] += __shfl_xor(lsum[g], 32);
    }
    // epilogue: O rows are quad*4+r; lsum rows are l15 -> redistribute via shfl
    int b = bh >> 3, h = bh & 7;
#pragma unroll
    for (int g = 0; g < 4; g++)
#pragma unroll
        for (int r = 0; r < 4; r++) {
            float inv = 1.0f / __shfl(lsum[g], quad * 4 + r);
            int qr = qb0 + w * 64 + g * 16 + quad * 4 + r;
            size_t rowoff = ((size_t)(b * 4096 + qr)) * 512 + h * 64;
#pragma unroll
            for (int nt = 0; nt < 4; nt++)
                ctx[rowoff + nt * 16 + l15] = f2b(O[g][nt][r] * inv);
        }
}

// ---------------- out GEMM: ctx[8192,512]bf16 x wout[512,512]fp32^T + bias -> fp32 ----
__global__ __launch_bounds__(256) void k_gemm_out(const u16* __restrict__ ab,
                                                  const float* __restrict__ wout,
                                                  const float* __restrict__ bias,
                                                  float* __restrict__ out) {
    __shared__ u16 As[128][40];
    __shared__ u16 Ws[64][40];
    const int tid = threadIdx.x;
    const int w = tid >> 6, lane = tid & 63, l15 = lane & 15, quad = lane >> 4;
    const int mb = blockIdx.x * 128, nb = blockIdx.y * 64;

    f32x4 acc[2][4];
#pragma unroll
    for (int i = 0; i < 2; i++)
#pragma unroll
        for (int j = 0; j < 4; j++) acc[i][j] = (f32x4){0.f, 0.f, 0.f, 0.f};

    for (int k0 = 0; k0 < 512; k0 += 32) {
        {
            int row = tid >> 1, cc = (tid & 1) * 16;
            const u16* g = &ab[(size_t)(mb + row) * 512 + k0 + cc];
            *(uint4*)&As[row][cc]     = *(const uint4*)g;
            *(uint4*)&As[row][cc + 8] = *(const uint4*)(g + 8);
            int wrow = tid >> 2, wseg = (tid & 3) * 8;
            const float* gw = &wout[(size_t)(nb + wrow) * 512 + k0 + wseg];
            float4 h0 = *(const float4*)gw, h1 = *(const float4*)(gw + 4);
            u16 ow[8] = { f2b(h0.x), f2b(h0.y), f2b(h0.z), f2b(h0.w),
                          f2b(h1.x), f2b(h1.y), f2b(h1.z), f2b(h1.w) };
            *(uint4*)&Ws[wrow][wseg] = *(uint4*)ow;
        }
        __syncthreads();
        bf16x8 a0 = *(const bf16x8*)&As[w * 32 + l15][quad * 8];
        bf16x8 a1 = *(const bf16x8*)&As[w * 32 + 16 + l15][quad * 8];
#pragma unroll
        for (int nt = 0; nt < 4; nt++) {
            bf16x8 bfr = *(const bf16x8*)&Ws[nt * 16 + l15][quad * 8];
            acc[0][nt] = mfma16(a0, bfr, acc[0][nt]);
            acc[1][nt] = mfma16(a1, bfr, acc[1][nt]);
        }
        __syncthreads();
    }
#pragma unroll
    for (int mt = 0; mt < 2; mt++)
#pragma unroll
        for (int nt = 0; nt < 4; nt++)
#pragma unroll
            for (int r = 0; r < 4; r++) {
                int m = mb + w * 32 + mt * 16 + quad * 4 + r;
                int n = nb + nt * 16 + l15;
                out[(size_t)m * 512 + n] = acc[mt][nt][r] + bias[n];
            }
}

extern "C" void kernel_launch(void* const* d_in, const int* in_sizes, int n_in,
                              void* d_out, int out_size, void* d_ws, size_t ws_size,
                              hipStream_t stream) {
    const float* x    = (const float*)d_in[0];
    const float* wqkv = (const float*)d_in[1];
    const float* bqkv = (const float*)d_in[2];
    const float* wout = (const float*)d_in[3];
    const float* bout = (const float*)d_in[4];
    const int*   win  = (const int*)d_in[5];
    float* out = (float*)d_out;

    // workspace: qkv (bf16, q/k row-major + v transposed) + ctx (bf16), ~34 MB
    u16* qkvb = (u16*)d_ws;
    u16* ctxb = qkvb + 3ull * 16 * 4096 * 64;

    k_gemm_qkv<<<dim3(64, 24), 256, 0, stream>>>(x, wqkv, bqkv, qkvb);
    k_attn<<<dim3(32, 16), 128, 0, stream>>>(qkvb, ctxb, win);
    k_gemm_out<<<dim3(64, 8), 256, 0, stream>>>(ctxb, wout, bout, out);
}

// Round 4
// 240.199 us; speedup vs baseline: 1.2530x; 1.2530x over previous
//
#include <hip/hip_runtime.h>
#include <hip/hip_bf16.h>

typedef unsigned short u16;
typedef __bf16 bf16x8 __attribute__((ext_vector_type(8)));
typedef short s16x4 __attribute__((ext_vector_type(4)));
typedef float f32x4 __attribute__((ext_vector_type(4)));

__device__ __forceinline__ f32x4 mfma16(bf16x8 a, bf16x8 b, f32x4 c) {
    return __builtin_amdgcn_mfma_f32_16x16x32_bf16(a, b, c, 0, 0, 0);
}
__device__ __forceinline__ f32x4 mfma16k16(s16x4 a, s16x4 b, f32x4 c) {
    return __builtin_amdgcn_mfma_f32_16x16x16bf16_1k(a, b, c, 0, 0, 0);
}

// fp32 -> bf16 bits, round-to-nearest-even
__device__ __forceinline__ u16 f2b(float x) {
    union { float f; unsigned u; } a; a.f = x;
    unsigned r = a.u + 0x7fffu + ((a.u >> 16) & 1u);
    return (u16)(r >> 16);
}

// ---------------- cast fp32 -> bf16 ----------------
__global__ __launch_bounds__(256) void k_cast(const float* __restrict__ src,
                                              u16* __restrict__ dst, int n) {
    int i = (blockIdx.x * 256 + threadIdx.x) * 4;
    if (i >= n) return;
    float4 f = *(const float4*)&src[i];
    u16 o[4] = { f2b(f.x), f2b(f.y), f2b(f.z), f2b(f.w) };
    *(uint2*)&dst[i] = *(uint2*)o;
}

// ---------------- QKV GEMM: [8192,512]bf16 x [1536,512]bf16^T ----------------
// 128x128 tile. -> q,k [B*H,S,64] bf16 (q pre-scaled 0.125/ln2), v [B*H,64,S] bf16
__global__ __launch_bounds__(256) void k_gemm_qkv(const u16* __restrict__ xb,
                                                  const u16* __restrict__ wb,
                                                  const float* __restrict__ bias,
                                                  u16* __restrict__ qkvout) {
    __shared__ u16 As[128][40];
    __shared__ u16 Ws[128][40];
    const int tid = threadIdx.x;
    const int w = tid >> 6, lane = tid & 63, l15 = lane & 15, quad = lane >> 4;
    const int mb = blockIdx.x * 128, nb = blockIdx.y * 128;

    f32x4 acc[2][8];
#pragma unroll
    for (int i = 0; i < 2; i++)
#pragma unroll
        for (int j = 0; j < 8; j++) acc[i][j] = (f32x4){0.f, 0.f, 0.f, 0.f};

    for (int k0 = 0; k0 < 512; k0 += 32) {
        {
            int row = tid >> 1, cc = (tid & 1) * 16;
            const u16* g = &xb[(size_t)(mb + row) * 512 + k0 + cc];
            *(uint4*)&As[row][cc]     = *(const uint4*)g;
            *(uint4*)&As[row][cc + 8] = *(const uint4*)(g + 8);
            const u16* gw = &wb[(size_t)(nb + row) * 512 + k0 + cc];
            *(uint4*)&Ws[row][cc]     = *(const uint4*)gw;
            *(uint4*)&Ws[row][cc + 8] = *(const uint4*)(gw + 8);
        }
        __syncthreads();
        bf16x8 a0 = *(const bf16x8*)&As[w * 32 + l15][quad * 8];
        bf16x8 a1 = *(const bf16x8*)&As[w * 32 + 16 + l15][quad * 8];
#pragma unroll
        for (int nt = 0; nt < 8; nt++) {
            bf16x8 bfr = *(const bf16x8*)&Ws[nt * 16 + l15][quad * 8];
            acc[0][nt] = mfma16(a0, bfr, acc[0][nt]);
            acc[1][nt] = mfma16(a1, bfr, acc[1][nt]);
        }
        __syncthreads();
    }
    // epilogue: q,k -> [B*H][S][64]; v -> transposed [B*H][64][S]
    const int seg = nb >> 9;          // 0=q 1=k 2=v (128-tile stays in one seg)
    u16* obase = qkvout + (size_t)seg * (16ull * 4096 * 64);
    if (seg < 2) {
        const float sc = (seg == 0) ? 0.125f * 1.44269504088896340736f : 1.0f;
#pragma unroll
        for (int mt = 0; mt < 2; mt++)
#pragma unroll
            for (int nt = 0; nt < 8; nt++) {
                int dcol = nb + nt * 16 + l15;
                int hh = (dcol >> 6) & 7, dloc = dcol & 63;
                float bs = bias[dcol];
#pragma unroll
                for (int r = 0; r < 4; r++) {
                    int m = mb + w * 32 + mt * 16 + quad * 4 + r;
                    float vv = (acc[mt][nt][r] + bs) * sc;
                    int b = m >> 12, s = m & 4095;
                    obase[((size_t)((b * 8 + hh) * 4096 + s)) * 64 + dloc] = f2b(vv);
                }
            }
    } else {
#pragma unroll
        for (int mt = 0; mt < 2; mt++)
#pragma unroll
            for (int nt = 0; nt < 8; nt++) {
                int dcol = nb + nt * 16 + l15;
                int hh = (dcol >> 6) & 7, dloc = dcol & 63;
                float bs = bias[dcol];
                int m0 = mb + w * 32 + mt * 16 + quad * 4;
                int b = m0 >> 12, s0 = m0 & 4095;
                u16 o[4];
#pragma unroll
                for (int r = 0; r < 4; r++) o[r] = f2b(acc[mt][nt][r] + bs);
                *(uint2*)&obase[((size_t)((b * 8 + hh) * 64 + dloc)) * 4096 + s0] = *(uint2*)o;
            }
    }
}

// ---------------- flash attention v4 (inverted-window mask) -----------------
// block = 128 thr = 2 waves x 32 q-rows. P never touches LDS: S^T C-layout
// (qrow=l15, key=quad*4+r) IS the B-frag layout of mfma_f32_16x16x16bf16,
// so exp2(S^T) packs straight into PV B-frags; PV computes O^T = V^T * P^T.
__global__ __launch_bounds__(128, 2) void k_attn(const u16* __restrict__ qkv,
                                                 u16* __restrict__ ctx,
                                                 const int* __restrict__ win) {
    __shared__ u16 Ks[64][72];    // [key][d]
    __shared__ u16 Vt[64][72];    // [d][key]
    const int tid = threadIdx.x;
    const int w = tid >> 6, lane = tid & 63, l15 = lane & 15, quad = lane >> 4;
    const int bh = blockIdx.y;
    const int qb0 = blockIdx.x * 64;
    const int W = win[0];
    const u16* qg = qkv;
    const u16* kg = qkv + 16ull * 4096 * 64;
    const u16* vg = qkv + 32ull * 4096 * 64;   // [bh][64][4096]
    const size_t bhb = (size_t)bh * 4096 * 64;

    // Q fragments: B-operand of S^T = K*Q^T  (lane l15 = qrow within group)
    bf16x8 qf[2][2];
#pragma unroll
    for (int g = 0; g < 2; g++) {
        const u16* qrow = &qg[bhb + (size_t)(qb0 + w * 32 + g * 16 + l15) * 64];
        qf[g][0] = *(const bf16x8*)&qrow[quad * 8];
        qf[g][1] = *(const bf16x8*)&qrow[32 + quad * 8];
    }

    f32x4 O[2][4];   // O^T: [g][mb=d-block]; col=qrow=l15, row=d_loc=quad*4+reg
#pragma unroll
    for (int g = 0; g < 2; g++)
#pragma unroll
        for (int mb = 0; mb < 4; mb++) O[g][mb] = (f32x4){0.f, 0.f, 0.f, 0.f};
    float lsum[2] = {0.f, 0.f};

    const int srow = tid >> 1, shalf = (tid & 1) * 32;
    const u16* kgr = &kg[bhb + (size_t)srow * 64 + shalf];
    const u16* vgr = &vg[((size_t)bh * 64 + srow) * 4096 + shalf];

    for (int kb = 0; kb < 4096; kb += 64) {
        if (max(qb0 + 63 - kb, kb + 63 - qb0) <= W) continue;  // fully masked tile
        bool partial = (kb + 63 >= qb0 - W) && (kb <= qb0 + 63 + W);
        {   // stage K (row-major) and Vt (d-major in global): all b128
            const u16* kp = kgr + (size_t)kb * 64;
            *(uint4*)&Ks[srow][shalf]      = *(const uint4*)kp;
            *(uint4*)&Ks[srow][shalf + 8]  = *(const uint4*)(kp + 8);
            *(uint4*)&Ks[srow][shalf + 16] = *(const uint4*)(kp + 16);
            *(uint4*)&Ks[srow][shalf + 24] = *(const uint4*)(kp + 24);
            const u16* vp = vgr + kb;
            *(uint4*)&Vt[srow][shalf]      = *(const uint4*)vp;
            *(uint4*)&Vt[srow][shalf + 8]  = *(const uint4*)(vp + 8);
            *(uint4*)&Vt[srow][shalf + 16] = *(const uint4*)(vp + 16);
            *(uint4*)&Vt[srow][shalf + 24] = *(const uint4*)(vp + 24);
        }
        __syncthreads();
        // K fragments (A of S^T), shared across both q-row groups
        bf16x8 kf[4][2];
#pragma unroll
        for (int nt = 0; nt < 4; nt++) {
            kf[nt][0] = *(const bf16x8*)&Ks[nt * 16 + l15][quad * 8];
            kf[nt][1] = *(const bf16x8*)&Ks[nt * 16 + l15][32 + quad * 8];
        }
        // V^T A-frags for PV (m=d=l15, k=key=quad*4+j), group-independent
        s16x4 vf[4][4];
#pragma unroll
        for (int mb = 0; mb < 4; mb++)
#pragma unroll
            for (int nt = 0; nt < 4; nt++)
                vf[mb][nt] = *(const s16x4*)&Vt[mb * 16 + l15][nt * 16 + quad * 4];
#pragma unroll
        for (int g = 0; g < 2; g++) {
            f32x4 C[4];
#pragma unroll
            for (int nt = 0; nt < 4; nt++) {
                f32x4 z = (f32x4){0.f, 0.f, 0.f, 0.f};
                C[nt] = mfma16(kf[nt][0], qf[g][0], z);
                C[nt] = mfma16(kf[nt][1], qf[g][1], C[nt]);
            }
            // p = 2^s; masked -> 0; pack into PV B-frags (registers only)
            s16x4 pb[4];
            if (!partial) {
#pragma unroll
                for (int nt = 0; nt < 4; nt++)
#pragma unroll
                    for (int r = 0; r < 4; r++) {
                        float p = __builtin_amdgcn_exp2f(C[nt][r]);
                        lsum[g] += p;
                        pb[nt][r] = (short)f2b(p);
                    }
            } else {
                int qr = qb0 + w * 32 + g * 16 + l15;
#pragma unroll
                for (int nt = 0; nt < 4; nt++)
#pragma unroll
                    for (int r = 0; r < 4; r++) {
                        int key = kb + nt * 16 + quad * 4 + r;
                        int dd = qr - key; dd = dd < 0 ? -dd : dd;
                        float p = (dd <= W) ? 0.f : __builtin_amdgcn_exp2f(C[nt][r]);
                        lsum[g] += p;
                        pb[nt][r] = (short)f2b(p);
                    }
            }
            // O^T += V^T * P^T  (16x16x16, K=16 per step over 64 keys)
#pragma unroll
            for (int nt = 0; nt < 4; nt++)
#pragma unroll
                for (int mb = 0; mb < 4; mb++)
                    O[g][mb] = mfma16k16(vf[mb][nt], pb[nt], O[g][mb]);
        }
        __syncthreads();
    }
    // deferred row-sums: reduce across the 4 quads (lsum lives at qrow=l15,
    // matching O^T's col=l15 -> no redistribution needed)
#pragma unroll
    for (int g = 0; g < 2; g++) {
        lsum[g] += __shfl_xor(lsum[g], 16);
        lsum[g] += __shfl_xor(lsum[g], 32);
    }
    int b = bh >> 3, h = bh & 7;
#pragma unroll
    for (int g = 0; g < 2; g++) {
        float inv = 1.0f / lsum[g];
        int qr = qb0 + w * 32 + g * 16 + l15;
        size_t rowoff = ((size_t)(b * 4096 + qr)) * 512 + h * 64;
#pragma unroll
        for (int mb = 0; mb < 4; mb++) {
            u16 o[4];
#pragma unroll
            for (int r = 0; r < 4; r++) o[r] = f2b(O[g][mb][r] * inv);
            *(uint2*)&ctx[rowoff + mb * 16 + quad * 4] = *(uint2*)o;
        }
    }
}

// ---------------- out GEMM: ctx[8192,512]bf16 x wout[512,512]bf16^T + bias -> fp32 ----
__global__ __launch_bounds__(256) void k_gemm_out(const u16* __restrict__ ab,
                                                  const u16* __restrict__ wb,
                                                  const float* __restrict__ bias,
                                                  float* __restrict__ out) {
    __shared__ u16 As[128][40];
    __shared__ u16 Ws[128][40];
    const int tid = threadIdx.x;
    const int w = tid >> 6, lane = tid & 63, l15 = lane & 15, quad = lane >> 4;
    const int mb = blockIdx.x * 128, nb = blockIdx.y * 128;

    f32x4 acc[2][8];
#pragma unroll
    for (int i = 0; i < 2; i++)
#pragma unroll
        for (int j = 0; j < 8; j++) acc[i][j] = (f32x4){0.f, 0.f, 0.f, 0.f};

    for (int k0 = 0; k0 < 512; k0 += 32) {
        {
            int row = tid >> 1, cc = (tid & 1) * 16;
            const u16* g = &ab[(size_t)(mb + row) * 512 + k0 + cc];
            *(uint4*)&As[row][cc]     = *(const uint4*)g;
            *(uint4*)&As[row][cc + 8] = *(const uint4*)(g + 8);
            const u16* gw = &wb[(size_t)(nb + row) * 512 + k0 + cc];
            *(uint4*)&Ws[row][cc]     = *(const uint4*)gw;
            *(uint4*)&Ws[row][cc + 8] = *(const uint4*)(gw + 8);
        }
        __syncthreads();
        bf16x8 a0 = *(const bf16x8*)&As[w * 32 + l15][quad * 8];
        bf16x8 a1 = *(const bf16x8*)&As[w * 32 + 16 + l15][quad * 8];
#pragma unroll
        for (int nt = 0; nt < 8; nt++) {
            bf16x8 bfr = *(const bf16x8*)&Ws[nt * 16 + l15][quad * 8];
            acc[0][nt] = mfma16(a0, bfr, acc[0][nt]);
            acc[1][nt] = mfma16(a1, bfr, acc[1][nt]);
        }
        __syncthreads();
    }
#pragma unroll
    for (int mt = 0; mt < 2; mt++)
#pragma unroll
        for (int nt = 0; nt < 8; nt++) {
            int n = nb + nt * 16 + l15;
            float bs = bias[n];
#pragma unroll
            for (int r = 0; r < 4; r++) {
                int m = mb + w * 32 + mt * 16 + quad * 4 + r;
                out[(size_t)m * 512 + n] = acc[mt][nt][r] + bs;
            }
        }
}

extern "C" void kernel_launch(void* const* d_in, const int* in_sizes, int n_in,
                              void* d_out, int out_size, void* d_ws, size_t ws_size,
                              hipStream_t stream) {
    const float* x    = (const float*)d_in[0];
    const float* wqkv = (const float*)d_in[1];
    const float* bqkv = (const float*)d_in[2];
    const float* wout = (const float*)d_in[3];
    const float* bout = (const float*)d_in[4];
    const int*   win  = (const int*)d_in[5];
    float* out = (float*)d_out;

    // workspace (u16 elements): x, wqkv, wout casts + qkv + ctx  (~44 MB)
    u16* xb    = (u16*)d_ws;
    u16* wqkvb = xb    + 8192ull * 512;
    u16* woutb = wqkvb + 1536ull * 512;
    u16* qkvb  = woutb + 512ull * 512;
    u16* ctxb  = qkvb  + 3ull * 16 * 4096 * 64;

    k_cast<<<4096, 256, 0, stream>>>(x, xb, 8192 * 512);
    k_cast<<<768, 256, 0, stream>>>(wqkv, wqkvb, 1536 * 512);
    k_cast<<<256, 256, 0, stream>>>(wout, woutb, 512 * 512);
    k_gemm_qkv<<<dim3(64, 12), 256, 0, stream>>>(xb, wqkvb, bqkv, qkvb);
    k_attn<<<dim3(64, 16), 128, 0, stream>>>(qkvb, ctxb, win);
    k_gemm_out<<<dim3(64, 4), 256, 0, stream>>>(ctxb, woutb, bout, out);
}